// Round 7
// baseline (209.285 us; speedup 1.0000x reference)
//
#include <hip/hip_runtime.h>
#include <hip/hip_bf16.h>

using bf16 = __hip_bfloat16;
typedef __bf16 bf16x8 __attribute__((ext_vector_type(8)));
typedef short short4v __attribute__((ext_vector_type(4)));
typedef short short8v __attribute__((ext_vector_type(8)));
typedef float float4v __attribute__((ext_vector_type(4)));

#define DIM   768
#define NH    12
#define HD    64
#define SEQ   2048
#define BATCH 4
#define TOK   (BATCH * SEQ)   // 8192
// softmax scale * log2(e) folded into q at QKV epilogue (flash uses exp2)
#define SCALE_QL2E 0.18033688011112042f

#define NX  (TOK * DIM)        // 6291456
#define NWQ (3 * DIM * DIM)    // 1769472
#define NWP (DIM * DIM)        //  589824

__device__ __forceinline__ short f2bf(float f) {
  union { bf16 h; short s; } u;
  u.h = __float2bfloat16(f);
  return u.s;
}

union frag8 { short4v h[2]; short8v s; bf16x8 b; };

// global(16B) -> LDS async DMA; LDS dest must be wave-uniform base + lane*16B
__device__ __forceinline__ void async_copy16(const bf16* g, short* l) {
  __builtin_amdgcn_global_load_lds(
      (const __attribute__((address_space(1))) unsigned int*)g,
      (__attribute__((address_space(3))) unsigned int*)l, 16, 0, 0);
}
// 4B variant (partial-row staging; dest = base + lane*4B)
__device__ __forceinline__ void async_copy4(const bf16* g, short* l) {
  __builtin_amdgcn_global_load_lds(
      (const __attribute__((address_space(1))) unsigned int*)g,
      (__attribute__((address_space(3))) unsigned int*)l, 4, 0, 0);
}

// ---------------------------------------------------------------------------
// Kernel 0: f32 -> bf16 convert for x, w_qkv, w_proj (one fused launch)
// ---------------------------------------------------------------------------
__global__ void __launch_bounds__(256)
cvt3(const float* __restrict__ a, bf16* __restrict__ oa, long na,
     const float* __restrict__ b, bf16* __restrict__ ob, long nb,
     const float* __restrict__ c, bf16* __restrict__ oc, long nc) {
  const long i = ((long)blockIdx.x * 256 + threadIdx.x) * 8;
  const float* src; bf16* dst; long off;
  if (i < na)                { src = a; dst = oa; off = i; }
  else if (i < na + nb)      { src = b; dst = ob; off = i - na; }
  else if (i < na + nb + nc) { src = c; dst = oc; off = i - na - nb; }
  else return;
  const float4v x0 = *(const float4v*)(src + off);
  const float4v x1 = *(const float4v*)(src + off + 4);
  short8v r;
  r[0] = f2bf(x0[0]); r[1] = f2bf(x0[1]); r[2] = f2bf(x0[2]); r[3] = f2bf(x0[3]);
  r[4] = f2bf(x1[0]); r[5] = f2bf(x1[1]); r[6] = f2bf(x1[2]); r[7] = f2bf(x1[3]);
  *(short8v*)(dst + off) = r;
}

// ---------------------------------------------------------------------------
// Shared 128x128 bf16 GEMM main loop (m97 structure) — still used by gemm_proj
// ---------------------------------------------------------------------------
__device__ __forceinline__ void gemm_mainloop(const bf16* __restrict__ A,
                                              const bf16* __restrict__ B,
                                              short* As, short* Bs,
                                              float4v acc[4][4]) {
  const int t = threadIdx.x;
  const int w = t >> 6, l = t & 63, lr = l & 15, q = l >> 4;
  const int wr = ((w >> 1) << 6), wc = ((w & 1) << 6);

  const bf16* Ag = A + (t >> 2) * DIM + (t & 3) * 8;
  const bf16* Bg = B + (t >> 2) * DIM + (t & 3) * 8;

  for (int k0 = 0; k0 < DIM; k0 += 32) {
    __syncthreads();                       // previous tile's consumers done
    async_copy16(Ag,            &As[t * 8]);
    async_copy16(Ag + 64 * DIM, &As[2048 + t * 8]);
    async_copy16(Bg,            &Bs[t * 8]);
    async_copy16(Bg + 64 * DIM, &Bs[2048 + t * 8]);
    Ag += 32; Bg += 32;
    __syncthreads();                       // vmcnt(0) drain before barrier

    bf16x8 af[4], bfv[4];
#pragma unroll
    for (int i = 0; i < 4; ++i)
      af[i] = *(const bf16x8*)&As[(wr + i * 16 + lr) * 32 + q * 8];
#pragma unroll
    for (int j = 0; j < 4; ++j)
      bfv[j] = *(const bf16x8*)&Bs[(wc + j * 16 + lr) * 32 + q * 8];
#pragma unroll
    for (int i = 0; i < 4; ++i)
#pragma unroll
      for (int j = 0; j < 4; ++j)
        acc[i][j] = __builtin_amdgcn_mfma_f32_16x16x32_bf16(af[i], bfv[j],
                                                            acc[i][j], 0, 0, 0);
  }
}

// ---------------------------------------------------------------------------
// Kernel 1: QKV projection — r7: the r2-r4 KTILE 8-phase counted-vmcnt
// schedule (measured 3.26 TF/CU in-round) RE-TILED to a one-round grid.
//
// r6 post-mortem: r5/r6 coarsened the phases (36-MFMA monolithic) which is
// m196's measured regression; the KTILE structure was fine — only its
// 288-block grid (2-round makespan) was wrong.  Now: tile 256x288, grid
// 32x8 = 256 blocks = 1/CU, ONE round, fine phases, counted vmcnt.
//
// Geometry: 8 waves (512 thr), wave grid 4M x 2N (wm=w>>1, wn=w&1);
// per-wave 64 rows x 144 cols = 4 A-frags x 9 B-frags, INTERLEAVED strips:
// row(mf) = mf*64 + wm*16, col(nf) = nf<4 ? nf*32 + wn*16
//                                          : 128 + (nf-4)*32 + wn*16.
// So slot A0 = tile rows 0-127 (all waves' mf 0-1), A1 = rows 128-255,
// B0 = cols 0-127 (nf 0-3), B1 = cols 128-287 (160 rows; nf 4-8).
//
// LDS: 2 bufs x {A0 16K, A1 16K, B0 16K, B1 20K} = 136 KB, 1 block/CU.
// Slot loads: A0/A1/B0 = 2x16B; B1 = 2x16B (rows 0-127) + 2x4B (128-159).
//
// Per K-tile (BK=64, 2 panels), 4 phases (order caps frag liveness ~72 reg):
//  ph1: read a0(4)+b0(8) | ST1 | bar | lgkm | prio1 16 MFMA prio0 | bar
//  ph2: read a1(4)       | ST2 | bar | lgkm | prio1 16 MFMA prio0 | bar
//  ph3: read b1(10)      | ST3 | bar | lgkm | prio1 20 MFMA prio0 | bar
//  ph4:                    ST4 | bar |        prio1 20 MFMA prio0 | VW | bar
// Steady: KTILE(C, ST1=other.A1@+64, ST2=own.A0@+128, ST3=own.B0@+128,
// ST4=own.B1@+128, VW8).  vmcnt(8) = ST2+ST3+ST4 loads kept in flight;
// retires the other buf's 4 slots exactly before they're read (re-derived
// retire algebra for 2/2/2/4-load slots; mirrors r2-r4's verified VW6).
//
// LDS swizzle (r2-verified): 16B-slot index XOR row bits 1-2, pre-applied
// to the per-lane GLOBAL source col (rule #21).
// ---------------------------------------------------------------------------
#define VW8 asm volatile("s_waitcnt vmcnt(8)" ::: "memory")
#define VW0 asm volatile("s_waitcnt vmcnt(0)" ::: "memory")
#define BARRIER __builtin_amdgcn_s_barrier()
#define LGKM0 asm volatile("s_waitcnt lgkmcnt(0)" ::: "memory")
#define NOSTG (void)0
#define NOVW  (void)0

#define STG_A0(c, k) { async_copy16(pa    + (k),      &As0[c][t * 8]);        \
                       async_copy16(pa    + (k) + 32, &As0[c][4096 + t * 8]); }
#define STG_A1(c, k) { async_copy16(pa128 + (k),      &As1[c][t * 8]);        \
                       async_copy16(pa128 + (k) + 32, &As1[c][4096 + t * 8]); }
#define STG_B0(c, k) { async_copy16(pw0   + (k),      &Bs0[c][t * 8]);        \
                       async_copy16(pw0   + (k) + 32, &Bs0[c][4096 + t * 8]); }
#define STG_B1(c, k) { async_copy16(pw128 + (k),      &Bs1[c][t * 8]);        \
                       async_copy4 (pw256 + (k),      &Bs1[c][4096 + t * 2]); \
                       async_copy16(pw128 + (k) + 32, &Bs1[c][5120 + t * 8]); \
                       async_copy4 (pw256 + (k) + 32, &Bs1[c][9216 + t * 2]); }

#define KTILE(C, ST1, ST2, ST3, ST4, VW_) {                                   \
  bf16x8 a0[2][2], a1[2][2], b0[4][2], b1[5][2];                              \
  _Pragma("unroll") for (int m_ = 0; m_ < 2; ++m_) {                          \
    a0[m_][0] = *(const bf16x8*)&As0[C][m_ * 2048 + arow];                    \
    a0[m_][1] = *(const bf16x8*)&As0[C][4096 + m_ * 2048 + arow]; }           \
  _Pragma("unroll") for (int n_ = 0; n_ < 4; ++n_) {                          \
    b0[n_][0] = *(const bf16x8*)&Bs0[C][n_ * 1024 + brow];                    \
    b0[n_][1] = *(const bf16x8*)&Bs0[C][4096 + n_ * 1024 + brow]; }           \
  ST1; BARRIER; LGKM0;                                                        \
  __builtin_amdgcn_s_setprio(1);                                              \
  _Pragma("unroll") for (int m_ = 0; m_ < 2; ++m_)                            \
  _Pragma("unroll") for (int n_ = 0; n_ < 4; ++n_)                            \
  _Pragma("unroll") for (int p_ = 0; p_ < 2; ++p_)                            \
    acc[m_][n_] = __builtin_amdgcn_mfma_f32_16x16x32_bf16(                    \
        a0[m_][p_], b0[n_][p_], acc[m_][n_], 0, 0, 0);                        \
  __builtin_amdgcn_s_setprio(0); BARRIER;                                     \
  _Pragma("unroll") for (int m_ = 0; m_ < 2; ++m_) {                          \
    a1[m_][0] = *(const bf16x8*)&As1[C][m_ * 2048 + arow];                    \
    a1[m_][1] = *(const bf16x8*)&As1[C][4096 + m_ * 2048 + arow]; }           \
  ST2; BARRIER; LGKM0;                                                        \
  __builtin_amdgcn_s_setprio(1);                                              \
  _Pragma("unroll") for (int m_ = 0; m_ < 2; ++m_)                            \
  _Pragma("unroll") for (int n_ = 0; n_ < 4; ++n_)                            \
  _Pragma("unroll") for (int p_ = 0; p_ < 2; ++p_)                            \
    acc[2 + m_][n_] = __builtin_amdgcn_mfma_f32_16x16x32_bf16(                \
        a1[m_][p_], b0[n_][p_], acc[2 + m_][n_], 0, 0, 0);                    \
  __builtin_amdgcn_s_setprio(0); BARRIER;                                     \
  _Pragma("unroll") for (int n_ = 0; n_ < 5; ++n_) {                          \
    b1[n_][0] = *(const bf16x8*)&Bs1[C][n_ * 1024 + brow];                    \
    b1[n_][1] = *(const bf16x8*)&Bs1[C][5120 + n_ * 1024 + brow]; }           \
  ST3; BARRIER; LGKM0;                                                        \
  __builtin_amdgcn_s_setprio(1);                                              \
  _Pragma("unroll") for (int m_ = 0; m_ < 2; ++m_)                            \
  _Pragma("unroll") for (int n_ = 0; n_ < 5; ++n_)                            \
  _Pragma("unroll") for (int p_ = 0; p_ < 2; ++p_)                            \
    acc[m_][4 + n_] = __builtin_amdgcn_mfma_f32_16x16x32_bf16(                \
        a0[m_][p_], b1[n_][p_], acc[m_][4 + n_], 0, 0, 0);                    \
  __builtin_amdgcn_s_setprio(0); BARRIER;                                     \
  ST4; BARRIER;                                                               \
  __builtin_amdgcn_s_setprio(1);                                              \
  _Pragma("unroll") for (int m_ = 0; m_ < 2; ++m_)                            \
  _Pragma("unroll") for (int n_ = 0; n_ < 5; ++n_)                            \
  _Pragma("unroll") for (int p_ = 0; p_ < 2; ++p_)                            \
    acc[2 + m_][4 + n_] = __builtin_amdgcn_mfma_f32_16x16x32_bf16(            \
        a1[m_][p_], b1[n_][p_], acc[2 + m_][4 + n_], 0, 0, 0);                \
  __builtin_amdgcn_s_setprio(0); VW_; BARRIER; }

__global__ void __launch_bounds__(512, 2)
gemm_qkv(const bf16* __restrict__ X, const bf16* __restrict__ W,
         const float* __restrict__ bias,
         bf16* __restrict__ qb, bf16* __restrict__ kb, bf16* __restrict__ vb) {
  __shared__ short As0[2][8192];    // rows   0-127, 2 K-panels of [128][32]
  __shared__ short As1[2][8192];    // rows 128-255
  __shared__ short Bs0[2][8192];    // cols   0-127
  __shared__ short Bs1[2][10240];   // cols 128-287 (160 rows, [160][32] x2)
  const int t = threadIdx.x;
  const int w = t >> 6, l = t & 63, lr = l & 15, q = l >> 4;
  const int wm = w >> 1, wn = w & 1;          // 4M x 2N wave grid

  // XCD-aware bijective swizzle: 256 blocks, 32/XCD; each XCD owns 4
  // consecutive M-tiles x all 8 N-tiles (W panels L2-resident).
  const int orig = blockIdx.x;
  const int swz = (orig & 7) * 32 + (orig >> 3);
  const int tm = swz >> 3, tn = swz & 7;
  const int row0 = tm * 256, col0 = tn * 288;

  // staging coords: 16B loads: row sr = t>>2, 16B-slot t&3, source col
  // pre-swizzled by key(row) = row bits 1-2 (r2-verified involution)
  const int sr = t >> 2;
  const int scol = (((t & 3) << 3) ^ (((sr >> 1) & 3) << 3));
  const bf16* pa    = X + (size_t)(row0 + sr) * DIM + scol;
  const bf16* pa128 = X + (size_t)(row0 + 128 + sr) * DIM + scol;
  const bf16* pw0   = W + (size_t)(col0 + sr) * DIM + scol;
  const bf16* pw128 = W + (size_t)(col0 + 128 + sr) * DIM + scol;
  // B1 4B loads (slot rows 128-159 = cols 256-287): row 256+(t>>4)
  const int r4 = t >> 4;
  const int c4s = ((t & 15) << 1) ^ (((r4 >> 1) & 3) << 3);
  const bf16* pw256 = W + (size_t)(col0 + 256 + r4) * DIM + c4s;

  // fragment-read coords: frag row = 16*base + lr -> key from lr only
  const int acol = ((q << 3) ^ (((lr >> 1) & 3) << 3));
  const int arow = (wm * 16 + lr) * 32 + acol;
  const int brow = (wn * 16 + lr) * 32 + acol;

  float4v acc[4][9] = {};

  // prologue: tile0 -> buf0 (all 4 slots, 10 loads), tile1 -> buf1
  // (A0,B0,B1, 8 loads); vmcnt(8) retires buf0, keeps buf1 in flight.
  STG_A0(0, 0); STG_B0(0, 0); STG_B1(0, 0); STG_A1(0, 0);
  STG_A0(1, 64); STG_B0(1, 64); STG_B1(1, 64);
  VW8; BARRIER;

#pragma unroll 1
  for (int i = 0; i < 5; ++i) {
    // pointers at K = 128*i; tile 2i+1 = +64, 2i+2 = +128, 2i+3 = +192
    KTILE(0, STG_A1(1, 64),  STG_A0(0, 128), STG_B0(0, 128), STG_B1(0, 128), VW8)
    KTILE(1, STG_A1(0, 128), STG_A0(1, 192), STG_B0(1, 192), STG_B1(1, 192), VW8)
    pa += 128; pa128 += 128; pw0 += 128; pw128 += 128; pw256 += 128;
  }
  // epilogue: tiles 10 (buf0) & 11 (buf1); complete tile 11's A1, drain.
  KTILE(0, STG_A1(1, 64), NOSTG, NOSTG, NOSTG, VW0)
  KTILE(1, NOSTG, NOSTG, NOSTG, NOSTG, NOVW)

  // C-write: rows row0 + mf*64 + wm*16 + q*4 + r ;
  // cols col0 + (nf<4 ? nf*32 : 128+(nf-4)*32) + wn*16 + lr.
#pragma unroll
  for (int nf = 0; nf < 9; ++nf) {
    const int bcol = (nf < 4) ? nf * 32 : 128 + (nf - 4) * 32;
    const int gn = col0 + bcol + wn * 16 + lr;       // 0..2303
    const int which = gn / DIM;                      // uniform per frag
    const int cc = gn - which * DIM;
    const int hh = cc >> 6, dd = cc & 63;
    const float bv = bias[gn];
#pragma unroll
    for (int mf = 0; mf < 4; ++mf) {
      const int gm0 = row0 + mf * 64 + wm * 16 + (q << 2);  // token base (x4)
      const int b = gm0 >> 11, n0 = gm0 & 2047;
      if (which == 2) {
        short4v pv;
#pragma unroll
        for (int r = 0; r < 4; ++r) pv[r] = f2bf(acc[mf][nf][r] + bv);
        *(short4v*)&vb[((size_t)(b * NH + hh) * HD + dd) * SEQ + n0] = pv;
      } else {
        bf16* dst = (which == 0) ? qb : kb;
        const float sc = (which == 0) ? SCALE_QL2E : 1.0f;
#pragma unroll
        for (int r = 0; r < 4; ++r)
          dst[((size_t)(b * NH + hh) * SEQ + n0 + r) * HD + dd] =
              __float2bfloat16((acc[mf][nf][r] + bv) * sc);
      }
    }
  }
}

// ---------------------------------------------------------------------------
// Kernel 2: flash attention — r4 structure: KVBLK=64, double-buffered K/V,
// one barrier per kv-tile, l-sum via MFMA ones-trick, setprio on MFMA.
// (frozen; 66 us = 780 TF eff.)
// ---------------------------------------------------------------------------
__global__ void __launch_bounds__(256, 3)
flash_attn(const bf16* __restrict__ Qp, const bf16* __restrict__ Kp,
           const bf16* __restrict__ Vtp, bf16* __restrict__ Op) {
  const int bh = blockIdx.y, qt = blockIdx.x;
  const int t = threadIdx.x, w = t >> 6, l = t & 63, lr = l & 15, q = l >> 4;
  __shared__ short Ks[2][64 * 68];   // K tile [kk][d], dbuf, pad 64->68
  __shared__ short Vt[2][64 * 66];   // V^T tile [d][kk], dbuf, pad 64->66

  const bf16* Qb = Qp  + (size_t)(bh * SEQ + qt * 128) * HD;
  const bf16* Kb = Kp  + (size_t)bh * SEQ * HD;
  const bf16* Vb = Vtp + (size_t)bh * HD * SEQ;   // [d][n]

  const int tr3 = t >> 3, td8 = (t & 7) * 8;     // 32 rows x 64 cols per pass

  // stage Q [128][64]: rows 0-63 -> Ks[0], rows 64-127 -> Ks[1]
#pragma unroll
  for (int i = 0; i < 4; ++i) {
    const int row = i * 32 + tr3;
    *(short8v*)&Ks[row >> 6][(row & 63) * 68 + td8] =
        *(const short8v*)(Qb + (size_t)row * HD + td8);
  }
  __syncthreads();
  bf16x8 qf[2][2];
#pragma unroll
  for (int it = 0; it < 2; ++it)
#pragma unroll
    for (int kq = 0; kq < 2; ++kq) {
      const int row = w * 32 + it * 16 + lr;
      qf[it][kq] = *(const bf16x8*)&Ks[row >> 6][(row & 63) * 68 + kq * 32 + q * 8];
    }
  __syncthreads();   // all Q frags in regs before kt=0 overwrites Ks[0]

  // prefetch K/V tile 0 into registers
  short8v kr[2], vr[2];
#pragma unroll
  for (int i = 0; i < 2; ++i) {
    kr[i] = *(const short8v*)(Kb + (size_t)(i * 32 + tr3) * HD + td8);
    vr[i] = *(const short8v*)(Vb + (size_t)(i * 32 + tr3) * SEQ + td8);
  }

  frag8 ones;            // all-ones bf16 B-fragment for the l row-sum MFMA
#pragma unroll
  for (int r = 0; r < 8; ++r) ones.s[r] = (short)0x3F80;

  float4v o[2][4] = {};
  float4v lacc[2] = {};  // l, col-replicated in C/D layout

  for (int kt = 0; kt < 32; ++kt) {
    const int cur = kt & 1;
    // write tile kt (regs->LDS); issue prefetch kt+1 (hides under compute)
#pragma unroll
    for (int i = 0; i < 2; ++i) {
      *(short8v*)&Ks[cur][(i * 32 + tr3) * 68 + td8] = kr[i];
      *(short8v*)&Vt[cur][(i * 32 + tr3) * 66 + td8] = vr[i];
    }
    if (kt < 31) {
      const int k1 = (kt + 1) * 64;
#pragma unroll
      for (int i = 0; i < 2; ++i) {
        kr[i] = *(const short8v*)(Kb + (size_t)(k1 + i * 32 + tr3) * HD + td8);
        vr[i] = *(const short8v*)(Vb + (size_t)(i * 32 + tr3) * SEQ + k1 + td8);
      }
    }
    __syncthreads();

    // S^T = K * Q^T : tiles [kk 4][qr 2]
    float4v s[4][2] = {};
    __builtin_amdgcn_s_setprio(1);
#pragma unroll
    for (int jn = 0; jn < 4; ++jn) {
      bf16x8 kf[2];
#pragma unroll
      for (int kq = 0; kq < 2; ++kq)
        kf[kq] = *(const bf16x8*)&Ks[cur][(jn * 16 + lr) * 68 + kq * 32 + q * 8];
#pragma unroll
      for (int it = 0; it < 2; ++it)
#pragma unroll
        for (int kq = 0; kq < 2; ++kq)
          s[jn][it] = __builtin_amdgcn_mfma_f32_16x16x32_bf16(kf[kq], qf[it][kq],
                                                              s[jn][it], 0, 0, 0);
    }
    __builtin_amdgcn_s_setprio(0);

    // p = exp2(s), pack pairs: slot (q,j) <-> kk = 32c + 16*(j>>2) + 4q + (j&3)
    frag8 pf[2][2];
#pragma unroll
    for (int it = 0; it < 2; ++it)
#pragma unroll
      for (int c4 = 0; c4 < 2; ++c4)
#pragma unroll
        for (int r = 0; r < 4; ++r) {
          pf[c4][it].s[r]     = f2bf(__builtin_amdgcn_exp2f(s[2 * c4][it][r]));
          pf[c4][it].s[4 + r] = f2bf(__builtin_amdgcn_exp2f(s[2 * c4 + 1][it][r]));
        }

    // O += P * V ; l += P * 1  (B mirrors the paired-k slot mapping)
    __builtin_amdgcn_s_setprio(1);
#pragma unroll
    for (int c4 = 0; c4 < 2; ++c4) {
#pragma unroll
      for (int dj = 0; dj < 4; ++dj) {
        frag8 vf;
        vf.h[0] = *(const short4v*)&Vt[cur][(dj * 16 + lr) * 66 + c4 * 32 + (q << 2)];
        vf.h[1] = *(const short4v*)&Vt[cur][(dj * 16 + lr) * 66 + c4 * 32 + 16 + (q << 2)];
#pragma unroll
        for (int it = 0; it < 2; ++it)
          o[it][dj] = __builtin_amdgcn_mfma_f32_16x16x32_bf16(pf[c4][it].b, vf.b,
                                                              o[it][dj], 0, 0, 0);
      }
#pragma unroll
      for (int it = 0; it < 2; ++it)
        lacc[it] = __builtin_amdgcn_mfma_f32_16x16x32_bf16(pf[c4][it].b, ones.b,
                                                           lacc[it], 0, 0, 0);
    }
    __builtin_amdgcn_s_setprio(0);
  }

  // epilogue: linv directly per lane (lacc col-replicated), no shuffles
  const int b = bh / NH, h = bh - b * NH;
#pragma unroll
  for (int it = 0; it < 2; ++it)
#pragma unroll
    for (int r = 0; r < 4; ++r) {
      const float linv = 1.0f / lacc[it][r];
      const int grow = b * SEQ + qt * 128 + w * 32 + it * 16 + (q << 2) + r;
      bf16* orow = Op + (size_t)grow * DIM + h * HD;
#pragma unroll
      for (int dj = 0; dj < 4; ++dj)
        orow[dj * 16 + lr] = __float2bfloat16(o[it][dj][r] * linv);
    }
}

// ---------------------------------------------------------------------------
// Kernel 3: output projection.  AO[8192,768](bf16) @ w_proj^T(bf16) + b -> f32
// (unchanged this round)
// ---------------------------------------------------------------------------
__global__ void __launch_bounds__(256)
gemm_proj(const bf16* __restrict__ A, const bf16* __restrict__ W,
          const float* __restrict__ bias, float* __restrict__ out) {
  __shared__ short As[128 * 32];
  __shared__ short Bs[128 * 32];
  const int t = threadIdx.x;
  const int w = t >> 6, l = t & 63, lr = l & 15, q = l >> 4;
  const int wr = ((w >> 1) << 6), wc = ((w & 1) << 6);
  const int row0 = blockIdx.y * 128, col0 = blockIdx.x * 128;

  float4v acc[4][4] = {};
  gemm_mainloop(A + row0 * DIM, W + col0 * DIM, As, Bs, acc);

#pragma unroll
  for (int j = 0; j < 4; ++j) {
    const int gn = col0 + wc + j * 16 + lr;
    const float bv = bias[gn];
#pragma unroll
    for (int i = 0; i < 4; ++i) {
#pragma unroll
      for (int r = 0; r < 4; ++r) {
        const int gm = row0 + wr + i * 16 + (q << 2) + r;
        out[(size_t)gm * DIM + gn] = acc[i][j][r] + bv;
      }
    }
  }
}

// ---------------------------------------------------------------------------
extern "C" void kernel_launch(void* const* d_in, const int* in_sizes, int n_in,
                              void* d_out, int out_size, void* d_ws, size_t ws_size,
                              hipStream_t stream) {
  const float* x      = (const float*)d_in[0];
  const float* w_qkv  = (const float*)d_in[1];
  const float* b_qkv  = (const float*)d_in[2];
  const float* w_proj = (const float*)d_in[3];
  const float* b_proj = (const float*)d_in[4];
  float* out = (float*)d_out;

  const size_t perbuf = (size_t)BATCH * NH * SEQ * HD;  // 6291456 elems
  bf16* qb  = (bf16*)d_ws;
  bf16* kb  = qb + perbuf;
  bf16* vb  = kb + perbuf;          // [B,H,64,N] transposed
  bf16* ao  = vb + perbuf;
  bf16* xb  = ao + perbuf;          // NX
  bf16* wqb = xb + (size_t)NX;      // NWQ
  bf16* wpb = wqb + (size_t)NWQ;    // NWP

  const int cvt_blocks = (NX + NWQ + NWP) / 8 / 256;   // 4224
  cvt3<<<cvt_blocks, 256, 0, stream>>>(x, xb, NX, w_qkv, wqb, NWQ, w_proj, wpb, NWP);
  gemm_qkv <<<dim3(256), 512, 0, stream>>>(xb, wqb, b_qkv, qb, kb, vb);
  flash_attn<<<dim3(SEQ / 128, BATCH * NH), 256, 0, stream>>>(qb, kb, vb, ao);
  gemm_proj <<<dim3(DIM / 128, TOK / 128),  256, 0, stream>>>(ao, wpb, b_proj, out);
}

// Round 8
// 206.574 us; speedup vs baseline: 1.0131x; 1.0131x over previous
//
#include <hip/hip_runtime.h>
#include <hip/hip_bf16.h>

using bf16 = __hip_bfloat16;
typedef __bf16 bf16x8 __attribute__((ext_vector_type(8)));
typedef short short4v __attribute__((ext_vector_type(4)));
typedef short short8v __attribute__((ext_vector_type(8)));
typedef float float4v __attribute__((ext_vector_type(4)));

#define DIM   768
#define NH    12
#define HD    64
#define SEQ   2048
#define BATCH 4
#define TOK   (BATCH * SEQ)   // 8192
// softmax scale * log2(e) folded into q at QKV epilogue (flash uses exp2)
#define SCALE_QL2E 0.18033688011112042f

#define NX  (TOK * DIM)        // 6291456
#define NWQ (3 * DIM * DIM)    // 1769472
#define NWP (DIM * DIM)        //  589824

__device__ __forceinline__ short f2bf(float f) {
  union { bf16 h; short s; } u;
  u.h = __float2bfloat16(f);
  return u.s;
}

union frag8 { short4v h[2]; short8v s; bf16x8 b; };

// global(16B) -> LDS async DMA; LDS dest must be wave-uniform base + lane*16B
__device__ __forceinline__ void async_copy16(const bf16* g, short* l) {
  __builtin_amdgcn_global_load_lds(
      (const __attribute__((address_space(1))) unsigned int*)g,
      (__attribute__((address_space(3))) unsigned int*)l, 16, 0, 0);
}
// 4B variant (partial-row staging; dest = base + lane*4B)
__device__ __forceinline__ void async_copy4(const bf16* g, short* l) {
  __builtin_amdgcn_global_load_lds(
      (const __attribute__((address_space(1))) unsigned int*)g,
      (__attribute__((address_space(3))) unsigned int*)l, 4, 0, 0);
}

#define BARRIER __builtin_amdgcn_s_barrier()
#define LGKM0 asm volatile("s_waitcnt lgkmcnt(0)" ::: "memory")
#define VW0 asm volatile("s_waitcnt vmcnt(0)" ::: "memory")
#define VW4 asm volatile("s_waitcnt vmcnt(4)" ::: "memory")
#define VW8 asm volatile("s_waitcnt vmcnt(8)" ::: "memory")
#define NOSTG (void)0
#define NOVW  (void)0

// ---------------------------------------------------------------------------
// Kernel 0: f32 -> bf16 convert for x, w_qkv, w_proj (one fused launch)
// ---------------------------------------------------------------------------
__global__ void __launch_bounds__(256)
cvt3(const float* __restrict__ a, bf16* __restrict__ oa, long na,
     const float* __restrict__ b, bf16* __restrict__ ob, long nb,
     const float* __restrict__ c, bf16* __restrict__ oc, long nc) {
  const long i = ((long)blockIdx.x * 256 + threadIdx.x) * 8;
  const float* src; bf16* dst; long off;
  if (i < na)                { src = a; dst = oa; off = i; }
  else if (i < na + nb)      { src = b; dst = ob; off = i - na; }
  else if (i < na + nb + nc) { src = c; dst = oc; off = i - na - nb; }
  else return;
  const float4v x0 = *(const float4v*)(src + off);
  const float4v x1 = *(const float4v*)(src + off + 4);
  short8v r;
  r[0] = f2bf(x0[0]); r[1] = f2bf(x0[1]); r[2] = f2bf(x0[2]); r[3] = f2bf(x0[3]);
  r[4] = f2bf(x1[0]); r[5] = f2bf(x1[1]); r[6] = f2bf(x1[2]); r[7] = f2bf(x1[3]);
  *(short8v*)(dst + off) = r;
}

// ---------------------------------------------------------------------------
// Shared 128x128 bf16 GEMM main loop (m97 structure) — still used by gemm_proj
// ---------------------------------------------------------------------------
__device__ __forceinline__ void gemm_mainloop(const bf16* __restrict__ A,
                                              const bf16* __restrict__ B,
                                              short* As, short* Bs,
                                              float4v acc[4][4]) {
  const int t = threadIdx.x;
  const int w = t >> 6, l = t & 63, lr = l & 15, q = l >> 4;
  const int wr = ((w >> 1) << 6), wc = ((w & 1) << 6);

  const bf16* Ag = A + (t >> 2) * DIM + (t & 3) * 8;
  const bf16* Bg = B + (t >> 2) * DIM + (t & 3) * 8;

  for (int k0 = 0; k0 < DIM; k0 += 32) {
    __syncthreads();                       // previous tile's consumers done
    async_copy16(Ag,            &As[t * 8]);
    async_copy16(Ag + 64 * DIM, &As[2048 + t * 8]);
    async_copy16(Bg,            &Bs[t * 8]);
    async_copy16(Bg + 64 * DIM, &Bs[2048 + t * 8]);
    Ag += 32; Bg += 32;
    __syncthreads();                       // vmcnt(0) drain before barrier

    bf16x8 af[4], bfv[4];
#pragma unroll
    for (int i = 0; i < 4; ++i)
      af[i] = *(const bf16x8*)&As[(wr + i * 16 + lr) * 32 + q * 8];
#pragma unroll
    for (int j = 0; j < 4; ++j)
      bfv[j] = *(const bf16x8*)&Bs[(wc + j * 16 + lr) * 32 + q * 8];
#pragma unroll
    for (int i = 0; i < 4; ++i)
#pragma unroll
      for (int j = 0; j < 4; ++j)
        acc[i][j] = __builtin_amdgcn_mfma_f32_16x16x32_bf16(af[i], bfv[j],
                                                            acc[i][j], 0, 0, 0);
  }
}

// ---------------------------------------------------------------------------
// Kernel 1: QKV projection — r6 version VERBATIM (measured best: 205.8 total).
// 128x288 tile, 512 blocks = 2 blocks/CU, dbuf-2, coarse 36-MFMA phases.
// r7 lesson: qkv is schedule-insensitive (+-10%) across 6 structural
// variants; r6 is the empirical minimum.  Frozen until counters surface.
// ---------------------------------------------------------------------------
#define STGP(s, p)                                                            \
  async_copy16(pa + (p) * 32,             &As[s][t * 8]);                     \
  async_copy16(pa + 64 * DIM + (p) * 32,  &As[s][2048 + t * 8]);              \
  async_copy16(pb + (p) * 32,             &Bs[s][t * 8]);                     \
  async_copy16(pb + 64 * DIM + (p) * 32,  &Bs[s][2048 + t * 8]);              \
  async_copy16(pb + 128 * DIM + (p) * 32, &Bs[s][4096 + t * 8]);              \
  async_copy16(pb + 192 * DIM + (p) * 32, &Bs[s][6144 + t * 8]);              \
  async_copy4 (pb3 + (p) * 32,            &Bs[s][8192 + t * 2]);              \
  async_copy4 (pb3 + 16 * DIM + (p) * 32, &Bs[s][8704 + t * 2])

#define PHASE(CUR, STG_, VW_) {                                               \
  bf16x8 af[4], bfv[9];                                                       \
  _Pragma("unroll") for (int mf_ = 0; mf_ < 4; ++mf_)                         \
    af[mf_] = *(const bf16x8*)&As[CUR][mf_ * 512 + arow];                     \
  _Pragma("unroll") for (int nf_ = 0; nf_ < 9; ++nf_)                         \
    bfv[nf_] = *(const bf16x8*)&Bs[CUR][nf_ * 512 + brow];                    \
  STG_; BARRIER; LGKM0;                                                       \
  __builtin_amdgcn_s_setprio(1);                                              \
  _Pragma("unroll") for (int mf_ = 0; mf_ < 4; ++mf_)                         \
  _Pragma("unroll") for (int nf_ = 0; nf_ < 9; ++nf_)                         \
    acc[mf_][nf_] = __builtin_amdgcn_mfma_f32_16x16x32_bf16(                  \
        af[mf_], bfv[nf_], acc[mf_][nf_], 0, 0, 0);                           \
  __builtin_amdgcn_s_setprio(0); VW_; BARRIER; }

__global__ void __launch_bounds__(256, 2)
gemm_qkv(const bf16* __restrict__ X, const bf16* __restrict__ W,
         const float* __restrict__ bias,
         bf16* __restrict__ qb, bf16* __restrict__ kb, bf16* __restrict__ vb) {
  __shared__ short As[2][128 * 32];   // 2 x 8 KB
  __shared__ short Bs[2][288 * 32];   // 2 x 18 KB   (total 52 KB, 2 blk/CU)
  const int t = threadIdx.x;
  const int w = t >> 6, l = t & 63, lr = l & 15, q = l >> 4;
  const int wm = w >> 1, wn = w & 1;          // 2M x 2N wave grid

  // XCD-aware bijective swizzle: 512 blocks, 64/XCD
  const int orig = blockIdx.x;
  const int swz = (orig & 7) * 64 + (orig >> 3);
  const int tm = swz >> 3, tn = swz & 7;
  const int row0 = tm * 128, col0 = tn * 288;

  const int sr = t >> 2;
  const int scol = (((t & 3) << 3) ^ (((sr >> 1) & 3) << 3));
  const bf16* pa  = X + (size_t)(row0 + sr) * DIM + scol;
  const bf16* pb  = W + (size_t)(col0 + sr) * DIM + scol;
  const int r3 = t >> 4;
  const int c3 = ((t & 15) << 1) ^ (((r3 >> 1) & 3) << 3);
  const bf16* pb3 = W + (size_t)(col0 + 256 + r3) * DIM + c3;

  const int acol = ((q << 3) ^ (((lr >> 1) & 3) << 3));
  const int arow = (wm * 64 + lr) * 32 + acol;    // + mf*512
  const int brow = (wn * 144 + lr) * 32 + acol;   // + nf*512

  float4v acc[4][9] = {};

  STGP(0, 0);
  VW0; BARRIER;

#pragma unroll 1
  for (int k = 0; k < 22; k += 2) {
    PHASE(0, STGP(1, k + 1), VW0)
    PHASE(1, STGP(0, k + 2), VW0)
  }
  PHASE(0, STGP(1, 23), VW0)   // k=22
  PHASE(1, NOSTG,       NOVW)  // k=23

#pragma unroll
  for (int nf = 0; nf < 9; ++nf) {
    const int gn = col0 + wn * 144 + nf * 16 + lr;   // 0..2303
    const int which = gn / DIM;                      // uniform per frag
    const int cc = gn - which * DIM;
    const int hh = cc >> 6, dd = cc & 63;
    const float bv = bias[gn];
#pragma unroll
    for (int mf = 0; mf < 4; ++mf) {
      const int gm0 = row0 + wm * 64 + mf * 16 + (q << 2);  // token base (x4)
      const int b = gm0 >> 11, n0 = gm0 & 2047;
      if (which == 2) {
        short4v pv;
#pragma unroll
        for (int r = 0; r < 4; ++r) pv[r] = f2bf(acc[mf][nf][r] + bv);
        *(short4v*)&vb[((size_t)(b * NH + hh) * HD + dd) * SEQ + n0] = pv;
      } else {
        bf16* dst = (which == 0) ? qb : kb;
        const float sc = (which == 0) ? SCALE_QL2E : 1.0f;
#pragma unroll
        for (int r = 0; r < 4; ++r)
          dst[((size_t)(b * NH + hh) * SEQ + n0 + r) * HD + dd] =
              __float2bfloat16((acc[mf][nf][r] + bv) * sc);
      }
    }
  }
}

// ---------------------------------------------------------------------------
// Kernel 2: flash attention — r8: K/V staged via global_load_lds DMA on a
// ring-4 (64 KB), counted vmcnt(8), ONE raw s_barrier per kv-tile.
//
// r7 counters: MfmaUtil 35 + VALUBusy 39.5, ~26% idle; per-kt VALU is
// dominated by the reg-roundtrip staging (8 glb loads + 8 ds_writes/thread)
// and its address math.  DMA removes that entirely (Common-mistake #1) and
// frees kr/vr (32 VGPR).  Q frags now load straight from global (coalesced
// 2KB per 16-lane group), deleting Q staging + 2 barriers.
//
// Ring-4 + single-barrier safety: STG at iter k targets buf[(k+2)&3],
// last read by COMPUTE(k-2) in span (B_{k-2},B_{k-1}); the STG sits in
// span (B_{k-1},B_k) — separated by B_{k-1}.  vmcnt(8) keeps tiles k+1,k+2
// in flight (T4: never drain in-loop); tail: VW4 @ kt=30, VW0 @ kt=31.
// Prologue accounting: qf(8)+tile0(4) retire at iter-0's VW8 exactly.
//
// LDS layout linear (DMA constraint): KV[buf] = {K 64x64 | V^T 64x64}.
// Swizzle on the GLOBAL SOURCE col (rule #21), key = (row&7)*8 elems (16B
// granular); reads XOR the same key.  Bank model: K b128 reads uniform
// (8 lanes/16B-col x 8 cols = throughput floor); V b64 reads 2-way (free).
// ---------------------------------------------------------------------------
#define STG_KV(bb, k1)                                                        \
  async_copy16(Kb + (size_t)((k1) + drow) * HD + skey,       &KV[bb][t * 8]); \
  async_copy16(Kb + (size_t)((k1) + 32 + drow) * HD + skey,  &KV[bb][2048 + t * 8]); \
  async_copy16(Vb + (size_t)drow * SEQ + (k1) + skey,        &KV[bb][4096 + t * 8]); \
  async_copy16(Vb + (size_t)(32 + drow) * SEQ + (k1) + skey, &KV[bb][6144 + t * 8])

__global__ void __launch_bounds__(256, 2)
flash_attn(const bf16* __restrict__ Qp, const bf16* __restrict__ Kp,
           const bf16* __restrict__ Vtp, bf16* __restrict__ Op) {
  const int bh = blockIdx.y, qt = blockIdx.x;
  const int t = threadIdx.x, w = t >> 6, l = t & 63, lr = l & 15, q = l >> 4;
  __shared__ short KV[4][8192];   // ring-4: {K[64][64] | V^T[64][64]}, 64 KB

  const bf16* Qb = Qp  + (size_t)(bh * SEQ + qt * 128) * HD;
  const bf16* Kb = Kp  + (size_t)bh * SEQ * HD;
  const bf16* Vb = Vtp + (size_t)bh * HD * SEQ;   // [d][n]

  // DMA coords: thread t -> dest row t>>3, 16B-slot t&7 (linear);
  // source col carries the inverse swizzle (involution)
  const int drow = t >> 3;
  const int skey = (((t & 7) ^ drow) & 7) * 8;

  // Q fragments straight from global
  bf16x8 qf[2][2];
#pragma unroll
  for (int it = 0; it < 2; ++it)
#pragma unroll
    for (int kq = 0; kq < 2; ++kq)
      qf[it][kq] = *(const bf16x8*)(Qb + (size_t)(w * 32 + it * 16 + lr) * HD +
                                    kq * 32 + q * 8);

  // read-side swizzle key: all frag rows have (row&7) == (lr&7)
  const int key8 = (lr & 7) << 3;

  frag8 ones;            // all-ones bf16 B-fragment for the l row-sum MFMA
#pragma unroll
  for (int r = 0; r < 8; ++r) ones.s[r] = (short)0x3F80;

  float4v o[2][4] = {};
  float4v lacc[2] = {};  // l, col-replicated in C/D layout

  STG_KV(0, 0);
  STG_KV(1, 64);

  for (int kt = 0; kt < 32; ++kt) {
    if (kt < 30) { STG_KV((kt + 2) & 3, (kt + 2) * 64); }
    if (kt < 30) { VW8; } else if (kt == 30) { VW4; } else { VW0; }
    BARRIER;                         // tile kt landed in KV[kt&3] for all waves
    const short* Bf = KV[kt & 3];

    // S^T = K * Q^T : tiles [kk 4][qr 2]
    float4v s[4][2] = {};
    __builtin_amdgcn_s_setprio(1);
#pragma unroll
    for (int jn = 0; jn < 4; ++jn) {
      bf16x8 kf[2];
#pragma unroll
      for (int kq = 0; kq < 2; ++kq)
        kf[kq] = *(const bf16x8*)&Bf[(jn * 16 + lr) * 64 +
                                     (((kq * 32) + (q << 3)) ^ key8)];
#pragma unroll
      for (int it = 0; it < 2; ++it)
#pragma unroll
        for (int kq = 0; kq < 2; ++kq)
          s[jn][it] = __builtin_amdgcn_mfma_f32_16x16x32_bf16(kf[kq], qf[it][kq],
                                                              s[jn][it], 0, 0, 0);
    }
    __builtin_amdgcn_s_setprio(0);

    // p = exp2(s), pack pairs: slot (q,j) <-> kk = 32c + 16*(j>>2) + 4q + (j&3)
    frag8 pf[2][2];
#pragma unroll
    for (int it = 0; it < 2; ++it)
#pragma unroll
      for (int c4 = 0; c4 < 2; ++c4)
#pragma unroll
        for (int r = 0; r < 4; ++r) {
          pf[c4][it].s[r]     = f2bf(__builtin_amdgcn_exp2f(s[2 * c4][it][r]));
          pf[c4][it].s[4 + r] = f2bf(__builtin_amdgcn_exp2f(s[2 * c4 + 1][it][r]));
        }

    // O += P * V ; l += P * 1  (B mirrors the paired-k slot mapping)
    __builtin_amdgcn_s_setprio(1);
#pragma unroll
    for (int c4 = 0; c4 < 2; ++c4) {
#pragma unroll
      for (int dj = 0; dj < 4; ++dj) {
        frag8 vf;
        vf.h[0] = *(const short4v*)&Bf[4096 + (dj * 16 + lr) * 64 +
                                       ((c4 * 32 + (q << 2)) ^ key8)];
        vf.h[1] = *(const short4v*)&Bf[4096 + (dj * 16 + lr) * 64 +
                                       ((c4 * 32 + 16 + (q << 2)) ^ key8)];
#pragma unroll
        for (int it = 0; it < 2; ++it)
          o[it][dj] = __builtin_amdgcn_mfma_f32_16x16x32_bf16(pf[c4][it].b, vf.b,
                                                              o[it][dj], 0, 0, 0);
      }
#pragma unroll
      for (int it = 0; it < 2; ++it)
        lacc[it] = __builtin_amdgcn_mfma_f32_16x16x32_bf16(pf[c4][it].b, ones.b,
                                                           lacc[it], 0, 0, 0);
    }
    __builtin_amdgcn_s_setprio(0);
  }

  // epilogue: linv directly per lane (lacc col-replicated), no shuffles
  const int b = bh / NH, h = bh - b * NH;
#pragma unroll
  for (int it = 0; it < 2; ++it)
#pragma unroll
    for (int r = 0; r < 4; ++r) {
      const float linv = 1.0f / lacc[it][r];
      const int grow = b * SEQ + qt * 128 + w * 32 + it * 16 + (q << 2) + r;
      bf16* orow = Op + (size_t)grow * DIM + h * HD;
#pragma unroll
      for (int dj = 0; dj < 4; ++dj)
        orow[dj * 16 + lr] = __float2bfloat16(o[it][dj][r] * linv);
    }
}

// ---------------------------------------------------------------------------
// Kernel 3: output projection.  AO[8192,768](bf16) @ w_proj^T(bf16) + b -> f32
// (unchanged this round)
// ---------------------------------------------------------------------------
__global__ void __launch_bounds__(256)
gemm_proj(const bf16* __restrict__ A, const bf16* __restrict__ W,
          const float* __restrict__ bias, float* __restrict__ out) {
  __shared__ short As[128 * 32];
  __shared__ short Bs[128 * 32];
  const int t = threadIdx.x;
  const int w = t >> 6, l = t & 63, lr = l & 15, q = l >> 4;
  const int wr = ((w >> 1) << 6), wc = ((w & 1) << 6);
  const int row0 = blockIdx.y * 128, col0 = blockIdx.x * 128;

  float4v acc[4][4] = {};
  gemm_mainloop(A + row0 * DIM, W + col0 * DIM, As, Bs, acc);

#pragma unroll
  for (int j = 0; j < 4; ++j) {
    const int gn = col0 + wc + j * 16 + lr;
    const float bv = bias[gn];
#pragma unroll
    for (int i = 0; i < 4; ++i) {
#pragma unroll
      for (int r = 0; r < 4; ++r) {
        const int gm = row0 + wr + i * 16 + (q << 2) + r;
        out[(size_t)gm * DIM + gn] = acc[i][j][r] + bv;
      }
    }
  }
}

// ---------------------------------------------------------------------------
extern "C" void kernel_launch(void* const* d_in, const int* in_sizes, int n_in,
                              void* d_out, int out_size, void* d_ws, size_t ws_size,
                              hipStream_t stream) {
  const float* x      = (const float*)d_in[0];
  const float* w_qkv  = (const float*)d_in[1];
  const float* b_qkv  = (const float*)d_in[2];
  const float* w_proj = (const float*)d_in[3];
  const float* b_proj = (const float*)d_in[4];
  float* out = (float*)d_out;

  const size_t perbuf = (size_t)BATCH * NH * SEQ * HD;  // 6291456 elems
  bf16* qb  = (bf16*)d_ws;
  bf16* kb  = qb + perbuf;
  bf16* vb  = kb + perbuf;          // [B,H,64,N] transposed
  bf16* ao  = vb + perbuf;
  bf16* xb  = ao + perbuf;          // NX
  bf16* wqb = xb + (size_t)NX;      // NWQ
  bf16* wpb = wqb + (size_t)NWQ;    // NWP

  const int cvt_blocks = (NX + NWQ + NWP) / 8 / 256;   // 4224
  cvt3<<<cvt_blocks, 256, 0, stream>>>(x, xb, NX, w_qkv, wqb, NWQ, w_proj, wpb, NWP);
  gemm_qkv <<<dim3(512), 256, 0, stream>>>(xb, wqb, b_qkv, qb, kb, vb);
  flash_attn<<<dim3(SEQ / 128, BATCH * NH), 256, 0, stream>>>(qb, kb, vb, ao);
  gemm_proj <<<dim3(DIM / 128, TOK / 128),  256, 0, stream>>>(ao, wpb, b_proj, out);
}

// Round 9
// 202.605 us; speedup vs baseline: 1.0330x; 1.0196x over previous
//
#include <hip/hip_runtime.h>
#include <hip/hip_bf16.h>

using bf16 = __hip_bfloat16;
typedef __bf16 bf16x8 __attribute__((ext_vector_type(8)));
typedef short short4v __attribute__((ext_vector_type(4)));
typedef short short8v __attribute__((ext_vector_type(8)));
typedef float float4v __attribute__((ext_vector_type(4)));

#define DIM   768
#define NH    12
#define HD    64
#define SEQ   2048
#define BATCH 4
#define TOK   (BATCH * SEQ)   // 8192
// softmax scale * log2(e) folded into q at QKV epilogue (flash uses exp2)
#define SCALE_QL2E 0.18033688011112042f

#define NX  (TOK * DIM)        // 6291456
#define NWQ (3 * DIM * DIM)    // 1769472
#define NWP (DIM * DIM)        //  589824

__device__ __forceinline__ short f2bf(float f) {
  union { bf16 h; short s; } u;
  u.h = __float2bfloat16(f);
  return u.s;
}

union frag8 { short4v h[2]; short8v s; bf16x8 b; };

// global(16B) -> LDS async DMA; LDS dest must be wave-uniform base + lane*16B
__device__ __forceinline__ void async_copy16(const bf16* g, short* l) {
  __builtin_amdgcn_global_load_lds(
      (const __attribute__((address_space(1))) unsigned int*)g,
      (__attribute__((address_space(3))) unsigned int*)l, 16, 0, 0);
}
// 4B variant (partial-row staging; dest = base + lane*4B)
__device__ __forceinline__ void async_copy4(const bf16* g, short* l) {
  __builtin_amdgcn_global_load_lds(
      (const __attribute__((address_space(1))) unsigned int*)g,
      (__attribute__((address_space(3))) unsigned int*)l, 4, 0, 0);
}

#define BARRIER __builtin_amdgcn_s_barrier()
#define LGKM0 asm volatile("s_waitcnt lgkmcnt(0)" ::: "memory")
#define VW0 asm volatile("s_waitcnt vmcnt(0)" ::: "memory")
#define NOSTG (void)0
#define NOVW  (void)0

// ---------------------------------------------------------------------------
// Kernel 0: f32 -> bf16 convert for x, w_qkv, w_proj (one fused launch)
// ---------------------------------------------------------------------------
__global__ void __launch_bounds__(256)
cvt3(const float* __restrict__ a, bf16* __restrict__ oa, long na,
     const float* __restrict__ b, bf16* __restrict__ ob, long nb,
     const float* __restrict__ c, bf16* __restrict__ oc, long nc) {
  const long i = ((long)blockIdx.x * 256 + threadIdx.x) * 8;
  const float* src; bf16* dst; long off;
  if (i < na)                { src = a; dst = oa; off = i; }
  else if (i < na + nb)      { src = b; dst = ob; off = i - na; }
  else if (i < na + nb + nc) { src = c; dst = oc; off = i - na - nb; }
  else return;
  const float4v x0 = *(const float4v*)(src + off);
  const float4v x1 = *(const float4v*)(src + off + 4);
  short8v r;
  r[0] = f2bf(x0[0]); r[1] = f2bf(x0[1]); r[2] = f2bf(x0[2]); r[3] = f2bf(x0[3]);
  r[4] = f2bf(x1[0]); r[5] = f2bf(x1[1]); r[6] = f2bf(x1[2]); r[7] = f2bf(x1[3]);
  *(short8v*)(dst + off) = r;
}

// ---------------------------------------------------------------------------
// Shared 128x128 bf16 GEMM main loop (m97 structure) — still used by gemm_proj
// ---------------------------------------------------------------------------
__device__ __forceinline__ void gemm_mainloop(const bf16* __restrict__ A,
                                              const bf16* __restrict__ B,
                                              short* As, short* Bs,
                                              float4v acc[4][4]) {
  const int t = threadIdx.x;
  const int w = t >> 6, l = t & 63, lr = l & 15, q = l >> 4;
  const int wr = ((w >> 1) << 6), wc = ((w & 1) << 6);

  const bf16* Ag = A + (t >> 2) * DIM + (t & 3) * 8;
  const bf16* Bg = B + (t >> 2) * DIM + (t & 3) * 8;

  for (int k0 = 0; k0 < DIM; k0 += 32) {
    __syncthreads();                       // previous tile's consumers done
    async_copy16(Ag,            &As[t * 8]);
    async_copy16(Ag + 64 * DIM, &As[2048 + t * 8]);
    async_copy16(Bg,            &Bs[t * 8]);
    async_copy16(Bg + 64 * DIM, &Bs[2048 + t * 8]);
    Ag += 32; Bg += 32;
    __syncthreads();                       // vmcnt(0) drain before barrier

    bf16x8 af[4], bfv[4];
#pragma unroll
    for (int i = 0; i < 4; ++i)
      af[i] = *(const bf16x8*)&As[(wr + i * 16 + lr) * 32 + q * 8];
#pragma unroll
    for (int j = 0; j < 4; ++j)
      bfv[j] = *(const bf16x8*)&Bs[(wc + j * 16 + lr) * 32 + q * 8];
#pragma unroll
    for (int i = 0; i < 4; ++i)
#pragma unroll
      for (int j = 0; j < 4; ++j)
        acc[i][j] = __builtin_amdgcn_mfma_f32_16x16x32_bf16(af[i], bfv[j],
                                                            acc[i][j], 0, 0, 0);
  }
}

// ---------------------------------------------------------------------------
// Kernel 1: QKV projection — r6 version VERBATIM (measured best).
// 128x288 tile, 512 blocks = 2 blocks/CU, dbuf-2, coarse 36-MFMA phases.
// qkv is schedule-insensitive (+-10%) across 6 structural variants; frozen.
// ---------------------------------------------------------------------------
#define STGP(s, p)                                                            \
  async_copy16(pa + (p) * 32,             &As[s][t * 8]);                     \
  async_copy16(pa + 64 * DIM + (p) * 32,  &As[s][2048 + t * 8]);              \
  async_copy16(pb + (p) * 32,             &Bs[s][t * 8]);                     \
  async_copy16(pb + 64 * DIM + (p) * 32,  &Bs[s][2048 + t * 8]);              \
  async_copy16(pb + 128 * DIM + (p) * 32, &Bs[s][4096 + t * 8]);              \
  async_copy16(pb + 192 * DIM + (p) * 32, &Bs[s][6144 + t * 8]);              \
  async_copy4 (pb3 + (p) * 32,            &Bs[s][8192 + t * 2]);              \
  async_copy4 (pb3 + 16 * DIM + (p) * 32, &Bs[s][8704 + t * 2])

#define PHASE(CUR, STG_, VW_) {                                               \
  bf16x8 af[4], bfv[9];                                                       \
  _Pragma("unroll") for (int mf_ = 0; mf_ < 4; ++mf_)                         \
    af[mf_] = *(const bf16x8*)&As[CUR][mf_ * 512 + arow];                     \
  _Pragma("unroll") for (int nf_ = 0; nf_ < 9; ++nf_)                         \
    bfv[nf_] = *(const bf16x8*)&Bs[CUR][nf_ * 512 + brow];                    \
  STG_; BARRIER; LGKM0;                                                       \
  __builtin_amdgcn_s_setprio(1);                                              \
  _Pragma("unroll") for (int mf_ = 0; mf_ < 4; ++mf_)                         \
  _Pragma("unroll") for (int nf_ = 0; nf_ < 9; ++nf_)                         \
    acc[mf_][nf_] = __builtin_amdgcn_mfma_f32_16x16x32_bf16(                  \
        af[mf_], bfv[nf_], acc[mf_][nf_], 0, 0, 0);                           \
  __builtin_amdgcn_s_setprio(0); VW_; BARRIER; }

__global__ void __launch_bounds__(256, 2)
gemm_qkv(const bf16* __restrict__ X, const bf16* __restrict__ W,
         const float* __restrict__ bias,
         bf16* __restrict__ qb, bf16* __restrict__ kb, bf16* __restrict__ vb) {
  __shared__ short As[2][128 * 32];   // 2 x 8 KB
  __shared__ short Bs[2][288 * 32];   // 2 x 18 KB   (total 52 KB, 2 blk/CU)
  const int t = threadIdx.x;
  const int w = t >> 6, l = t & 63, lr = l & 15, q = l >> 4;
  const int wm = w >> 1, wn = w & 1;          // 2M x 2N wave grid

  // XCD-aware bijective swizzle: 512 blocks, 64/XCD
  const int orig = blockIdx.x;
  const int swz = (orig & 7) * 64 + (orig >> 3);
  const int tm = swz >> 3, tn = swz & 7;
  const int row0 = tm * 128, col0 = tn * 288;

  const int sr = t >> 2;
  const int scol = (((t & 3) << 3) ^ (((sr >> 1) & 3) << 3));
  const bf16* pa  = X + (size_t)(row0 + sr) * DIM + scol;
  const bf16* pb  = W + (size_t)(col0 + sr) * DIM + scol;
  const int r3 = t >> 4;
  const int c3 = ((t & 15) << 1) ^ (((r3 >> 1) & 3) << 3);
  const bf16* pb3 = W + (size_t)(col0 + 256 + r3) * DIM + c3;

  const int acol = ((q << 3) ^ (((lr >> 1) & 3) << 3));
  const int arow = (wm * 64 + lr) * 32 + acol;    // + mf*512
  const int brow = (wn * 144 + lr) * 32 + acol;   // + nf*512

  float4v acc[4][9] = {};

  STGP(0, 0);
  VW0; BARRIER;

#pragma unroll 1
  for (int k = 0; k < 22; k += 2) {
    PHASE(0, STGP(1, k + 1), VW0)
    PHASE(1, STGP(0, k + 2), VW0)
  }
  PHASE(0, STGP(1, 23), VW0)   // k=22
  PHASE(1, NOSTG,       NOVW)  // k=23

#pragma unroll
  for (int nf = 0; nf < 9; ++nf) {
    const int gn = col0 + wn * 144 + nf * 16 + lr;   // 0..2303
    const int which = gn / DIM;                      // uniform per frag
    const int cc = gn - which * DIM;
    const int hh = cc >> 6, dd = cc & 63;
    const float bv = bias[gn];
#pragma unroll
    for (int mf = 0; mf < 4; ++mf) {
      const int gm0 = row0 + wm * 64 + mf * 16 + (q << 2);  // token base (x4)
      const int b = gm0 >> 11, n0 = gm0 & 2047;
      if (which == 2) {
        short4v pv;
#pragma unroll
        for (int r = 0; r < 4; ++r) pv[r] = f2bf(acc[mf][nf][r] + bv);
        *(short4v*)&vb[((size_t)(b * NH + hh) * HD + dd) * SEQ + n0] = pv;
      } else {
        bf16* dst = (which == 0) ? qb : kb;
        const float sc = (which == 0) ? SCALE_QL2E : 1.0f;
#pragma unroll
        for (int r = 0; r < 4; ++r)
          dst[((size_t)(b * NH + hh) * SEQ + n0 + r) * HD + dd] =
              __float2bfloat16((acc[mf][nf][r] + bv) * sc);
      }
    }
  }
}

// ---------------------------------------------------------------------------
// Kernel 2: flash attention — r9: "r8 done right".  K/V via global_load_lds
// DMA on a RING-2 (32 KB, vs r8's 64 KB ring-4) with one barrier per kt and
// the drain AFTER compute.
//
// r8 post-mortem: DMA itself was fine (correctness + swizzle passed) but
// the 64 KB ring capped residency at 2 blocks/CU (Occupancy 25->15.8) while
// the 768-block grid wants 3/CU — a 10 us occupancy loss that swamped the
// staging savings.  Ring-2 restores 3 blocks/CU (96 KB of 160) and keeps
// the DMA wins: no per-thread glb->reg->ds_write roundtrip, no kr/vr regs.
//
// Ring-2 single-barrier safety: per iter k = {STG->buf[(k+1)&1];
// compute(k) from buf[k&1]; VW0; barrier}.  STG(k+1) issues after B_{k-1};
// previous readers of buf[(k+1)&1] (compute(k-1)) finished before B_{k-1}
// -> no WAR.  Each wave drains its own DMA (VW0) before B_k -> tile k+1
// complete before any wave's compute(k+1) -> no RAW.  The VW0 sits after
// the MFMA cluster where co-resident blocks cover the stall (m97 mech).
//
// LDS layout linear (DMA constraint): KV[buf] = {K 64x64 | V^T 64x64}.
// Swizzle on the GLOBAL SOURCE col (rule #21), key = (row&7)*16B; reads
// XOR the same key (r8-verified, refcheck passed).
// ---------------------------------------------------------------------------
#define STG_KV(bb, k1)                                                        \
  async_copy16(Kb + (size_t)((k1) + drow) * HD + skey,       &KV[bb][t * 8]); \
  async_copy16(Kb + (size_t)((k1) + 32 + drow) * HD + skey,  &KV[bb][2048 + t * 8]); \
  async_copy16(Vb + (size_t)drow * SEQ + (k1) + skey,        &KV[bb][4096 + t * 8]); \
  async_copy16(Vb + (size_t)(32 + drow) * SEQ + (k1) + skey, &KV[bb][6144 + t * 8])

__global__ void __launch_bounds__(256, 3)
flash_attn(const bf16* __restrict__ Qp, const bf16* __restrict__ Kp,
           const bf16* __restrict__ Vtp, bf16* __restrict__ Op) {
  const int bh = blockIdx.y, qt = blockIdx.x;
  const int t = threadIdx.x, w = t >> 6, l = t & 63, lr = l & 15, q = l >> 4;
  __shared__ short KV[2][8192];   // ring-2: {K[64][64] | V^T[64][64]}, 32 KB

  const bf16* Qb = Qp  + (size_t)(bh * SEQ + qt * 128) * HD;
  const bf16* Kb = Kp  + (size_t)bh * SEQ * HD;
  const bf16* Vb = Vtp + (size_t)bh * HD * SEQ;   // [d][n]

  // DMA coords: thread t -> dest row t>>3, 16B-slot t&7 (linear);
  // source col carries the inverse swizzle (involution)
  const int drow = t >> 3;
  const int skey = (((t & 7) ^ drow) & 7) * 8;

  // Q fragments straight from global (once per kernel)
  bf16x8 qf[2][2];
#pragma unroll
  for (int it = 0; it < 2; ++it)
#pragma unroll
    for (int kq = 0; kq < 2; ++kq)
      qf[it][kq] = *(const bf16x8*)(Qb + (size_t)(w * 32 + it * 16 + lr) * HD +
                                    kq * 32 + q * 8);

  // read-side swizzle key: all frag rows have (row&7) == (lr&7)
  const int key8 = (lr & 7) << 3;

  frag8 ones;            // all-ones bf16 B-fragment for the l row-sum MFMA
#pragma unroll
  for (int r = 0; r < 8; ++r) ones.s[r] = (short)0x3F80;

  float4v o[2][4] = {};
  float4v lacc[2] = {};  // l, col-replicated in C/D layout

  // prologue: tile 0 -> buf 0, drain, barrier
  STG_KV(0, 0);
  VW0; BARRIER;

  for (int kt = 0; kt < 32; ++kt) {
    if (kt < 31) { STG_KV((kt + 1) & 1, (kt + 1) * 64); }
    const short* Bf = KV[kt & 1];

    // S^T = K * Q^T : tiles [kk 4][qr 2]
    float4v s[4][2] = {};
    __builtin_amdgcn_s_setprio(1);
#pragma unroll
    for (int jn = 0; jn < 4; ++jn) {
      bf16x8 kf[2];
#pragma unroll
      for (int kq = 0; kq < 2; ++kq)
        kf[kq] = *(const bf16x8*)&Bf[(jn * 16 + lr) * 64 +
                                     (((kq * 32) + (q << 3)) ^ key8)];
#pragma unroll
      for (int it = 0; it < 2; ++it)
#pragma unroll
        for (int kq = 0; kq < 2; ++kq)
          s[jn][it] = __builtin_amdgcn_mfma_f32_16x16x32_bf16(kf[kq], qf[it][kq],
                                                              s[jn][it], 0, 0, 0);
    }
    __builtin_amdgcn_s_setprio(0);

    // p = exp2(s), pack pairs: slot (q,j) <-> kk = 32c + 16*(j>>2) + 4q + (j&3)
    frag8 pf[2][2];
#pragma unroll
    for (int it = 0; it < 2; ++it)
#pragma unroll
      for (int c4 = 0; c4 < 2; ++c4)
#pragma unroll
        for (int r = 0; r < 4; ++r) {
          pf[c4][it].s[r]     = f2bf(__builtin_amdgcn_exp2f(s[2 * c4][it][r]));
          pf[c4][it].s[4 + r] = f2bf(__builtin_amdgcn_exp2f(s[2 * c4 + 1][it][r]));
        }

    // O += P * V ; l += P * 1  (B mirrors the paired-k slot mapping)
    __builtin_amdgcn_s_setprio(1);
#pragma unroll
    for (int c4 = 0; c4 < 2; ++c4) {
#pragma unroll
      for (int dj = 0; dj < 4; ++dj) {
        frag8 vf;
        vf.h[0] = *(const short4v*)&Bf[4096 + (dj * 16 + lr) * 64 +
                                       ((c4 * 32 + (q << 2)) ^ key8)];
        vf.h[1] = *(const short4v*)&Bf[4096 + (dj * 16 + lr) * 64 +
                                       ((c4 * 32 + 16 + (q << 2)) ^ key8)];
#pragma unroll
        for (int it = 0; it < 2; ++it)
          o[it][dj] = __builtin_amdgcn_mfma_f32_16x16x32_bf16(pf[c4][it].b, vf.b,
                                                              o[it][dj], 0, 0, 0);
      }
#pragma unroll
      for (int it = 0; it < 2; ++it)
        lacc[it] = __builtin_amdgcn_mfma_f32_16x16x32_bf16(pf[c4][it].b, ones.b,
                                                           lacc[it], 0, 0, 0);
    }
    __builtin_amdgcn_s_setprio(0);

    if (kt < 31) { VW0; BARRIER; }   // drain own DMA AFTER compute; next tile
  }

  // epilogue: linv directly per lane (lacc col-replicated), no shuffles
  const int b = bh / NH, h = bh - b * NH;
#pragma unroll
  for (int it = 0; it < 2; ++it)
#pragma unroll
    for (int r = 0; r < 4; ++r) {
      const float linv = 1.0f / lacc[it][r];
      const int grow = b * SEQ + qt * 128 + w * 32 + it * 16 + (q << 2) + r;
      bf16* orow = Op + (size_t)grow * DIM + h * HD;
#pragma unroll
      for (int dj = 0; dj < 4; ++dj)
        orow[dj * 16 + lr] = __float2bfloat16(o[it][dj][r] * linv);
    }
}

// ---------------------------------------------------------------------------
// Kernel 3: output projection.  AO[8192,768](bf16) @ w_proj^T(bf16) + b -> f32
// (unchanged this round)
// ---------------------------------------------------------------------------
__global__ void __launch_bounds__(256)
gemm_proj(const bf16* __restrict__ A, const bf16* __restrict__ W,
          const float* __restrict__ bias, float* __restrict__ out) {
  __shared__ short As[128 * 32];
  __shared__ short Bs[128 * 32];
  const int t = threadIdx.x;
  const int w = t >> 6, l = t & 63, lr = l & 15, q = l >> 4;
  const int wr = ((w >> 1) << 6), wc = ((w & 1) << 6);
  const int row0 = blockIdx.y * 128, col0 = blockIdx.x * 128;

  float4v acc[4][4] = {};
  gemm_mainloop(A + row0 * DIM, W + col0 * DIM, As, Bs, acc);

#pragma unroll
  for (int j = 0; j < 4; ++j) {
    const int gn = col0 + wc + j * 16 + lr;
    const float bv = bias[gn];
#pragma unroll
    for (int i = 0; i < 4; ++i) {
#pragma unroll
      for (int r = 0; r < 4; ++r) {
        const int gm = row0 + wr + i * 16 + (q << 2) + r;
        out[(size_t)gm * DIM + gn] = acc[i][j][r] + bv;
      }
    }
  }
}

// ---------------------------------------------------------------------------
extern "C" void kernel_launch(void* const* d_in, const int* in_sizes, int n_in,
                              void* d_out, int out_size, void* d_ws, size_t ws_size,
                              hipStream_t stream) {
  const float* x      = (const float*)d_in[0];
  const float* w_qkv  = (const float*)d_in[1];
  const float* b_qkv  = (const float*)d_in[2];
  const float* w_proj = (const float*)d_in[3];
  const float* b_proj = (const float*)d_in[4];
  float* out = (float*)d_out;

  const size_t perbuf = (size_t)BATCH * NH * SEQ * HD;  // 6291456 elems
  bf16* qb  = (bf16*)d_ws;
  bf16* kb  = qb + perbuf;
  bf16* vb  = kb + perbuf;          // [B,H,64,N] transposed
  bf16* ao  = vb + perbuf;
  bf16* xb  = ao + perbuf;          // NX
  bf16* wqb = xb + (size_t)NX;      // NWQ
  bf16* wpb = wqb + (size_t)NWQ;    // NWP

  const int cvt_blocks = (NX + NWQ + NWP) / 8 / 256;   // 4224
  cvt3<<<cvt_blocks, 256, 0, stream>>>(x, xb, NX, w_qkv, wqb, NWQ, w_proj, wpb, NWP);
  gemm_qkv <<<dim3(512), 256, 0, stream>>>(xb, wqb, b_qkv, qb, kb, vb);
  flash_attn<<<dim3(SEQ / 128, BATCH * NH), 256, 0, stream>>>(qb, kb, vb, ao);
  gemm_proj <<<dim3(DIM / 128, TOK / 128),  256, 0, stream>>>(ao, wpb, b_proj, out);
}